// Round 1
// baseline (32.600 us; speedup 1.0000x reference)
//
#include <hip/hip_runtime.h>

// GraycodeEncoder: X (B,N,3) f32 -> out (B,N,96) int32.
// Per coord dim (32 slots): [sign(raw>0), 31 graycode bits of |round(x)|].
// graycode g = v ^ (v>>1); slot s of a dim = bit s of w = (g<<1)|sign.
__global__ void graycode_kernel(const float* __restrict__ X,
                                int* __restrict__ out,
                                int n_out4) {
    int idx    = blockIdx.x * blockDim.x + threadIdx.x;
    int stride = gridDim.x * blockDim.x;
    for (int o4 = idx; o4 < n_out4; o4 += stride) {
        int o     = o4 << 2;          // first of 4 consecutive int32 outputs
        int point = o / 96;           // compiler emits magic-mul
        int c     = o - point * 96;   // 0..95, multiple of 4
        int dim   = c >> 5;           // 0..2
        int q     = c & 31;           // slot within dim, multiple of 4

        float x = X[point * 3 + dim];
        int raw = __float2int_rn(x);          // round-half-to-even == jnp.round
        unsigned int sign = (raw > 0) ? 1u : 0u;
        int v = (raw < 0) ? -raw : raw;
        unsigned int g = (unsigned int)(v ^ (v >> 1));
        unsigned int w = (g << 1) | sign;     // bit s == output slot s of this dim

        int4 r;
        r.x = (int)((w >> (q + 0)) & 1u);
        r.y = (int)((w >> (q + 1)) & 1u);
        r.z = (int)((w >> (q + 2)) & 1u);
        r.w = (int)((w >> (q + 3)) & 1u);
        reinterpret_cast<int4*>(out)[o4] = r;
    }
}

extern "C" void kernel_launch(void* const* d_in, const int* in_sizes, int n_in,
                              void* d_out, int out_size, void* d_ws, size_t ws_size,
                              hipStream_t stream) {
    const float* X = (const float*)d_in[0];
    int* out = (int*)d_out;

    // out_size = n_points * 96, always divisible by 4
    int n_out4 = out_size >> 2;

    const int block = 256;
    int blocks_needed = (n_out4 + block - 1) / block;
    int grid = blocks_needed < 8192 ? blocks_needed : 8192;

    graycode_kernel<<<grid, block, 0, stream>>>(X, out, n_out4);
}